// Round 6
// baseline (225.522 us; speedup 1.0000x reference)
//
#include <hip/hip_runtime.h>
#include <stdint.h>

#define N_NODES 50000
#define N_EDGES 800000
#define HF 128          // HEADS * OUT_F
#define NEG_SLOPE 0.2f
#define EPS_F 1e-8f

typedef __attribute__((ext_vector_type(8))) short short8;
typedef __attribute__((ext_vector_type(4))) float f32x4;

// ---------- helpers ----------
__device__ __forceinline__ float bf2f(unsigned short u) {
    union { unsigned int i; float f; } v; v.i = ((unsigned int)u) << 16; return v.f;
}
__device__ __forceinline__ unsigned short f2bf(float f) {
    union { unsigned int i; float f; } v; v.f = f;
    unsigned int b = v.i;
    unsigned int r = (b + 0x7FFFu + ((b >> 16) & 1u)) >> 16;   // round-to-nearest-even
    return (unsigned short)r;
}
__device__ __forceinline__ float leaky(float v) { return v > 0.f ? v : NEG_SLOPE * v; }
// f32 <-> f16 (IEEE half) via hardware cvt
__device__ __forceinline__ unsigned short f2h(float f) {
    _Float16 h = (_Float16)f; unsigned short u; __builtin_memcpy(&u, &h, 2); return u;
}
__device__ __forceinline__ float h2f(unsigned short u) {
    _Float16 h; __builtin_memcpy(&h, &u, 2); return (float)h;
}

// ---------- K0: dtype sniff ----------
__global__ void k_sniff(const void* x, const void* eidx, int* flags) {
    int l = threadIdx.x;  // 64 threads
    const unsigned short* xu = (const unsigned short*)x;
    float f = bf2f(xu[2 * l]);
    float af = fabsf(f);
    bool extreme = !(af <= 1e6f) || (f != 0.0f && af < 1e-7f);
    unsigned long long mask = __ballot(extreme);
    const unsigned int* eu = (const unsigned int*)eidx;
    unsigned int w = eu[2 * l + 1];
    unsigned long long mask2 = __ballot(w != 0u);
    if (l == 0) {
        flags[0] = (__popcll(mask) >= 8) ? 0 : 1;   // 1 = bf16 floats
        flags[1] = (__popcll(mask2) >= 4) ? 0 : 1;  // 1 = int64 indices
    }
}

// ---------- K1: normalize W->bf16, a->f32, edges->packed u32 (src|dst<<16), degree count ----------
__global__ void k_convert(const void* W, const void* a_src, const void* a_dst, const void* eidx,
                          unsigned short* Wbf, float* af, unsigned int* edgePk, int* counts,
                          const int* flags) {
    int i = blockIdx.x * blockDim.x + threadIdx.x;
    int isB = flags[0], is64 = flags[1];
    if (i < 16384) Wbf[i] = isB ? ((const unsigned short*)W)[i] : f2bf(((const float*)W)[i]);
    if (i < 128) {
        af[i]       = isB ? bf2f(((const unsigned short*)a_src)[i]) : ((const float*)a_src)[i];
        af[128 + i] = isB ? bf2f(((const unsigned short*)a_dst)[i]) : ((const float*)a_dst)[i];
    }
    if (i < N_EDGES) {
        int s, d;
        if (is64) {
            s = (int)((const long long*)eidx)[i];
            d = (int)((const long long*)eidx)[N_EDGES + i];
        } else {
            s = ((const int*)eidx)[i];
            d = ((const int*)eidx)[N_EDGES + i];
        }
        edgePk[i] = (unsigned int)s | ((unsigned int)d << 16);
        atomicAdd(&counts[d], 1);
    }
}

// ---------- K2: MFMA GEMM  h = x @ W^T (bf16), fused scores s_src/s_dst ----------
__global__ __launch_bounds__(256) void k_gemm(const void* x, const unsigned short* Wbf, const float* af,
                                              unsigned short* h, float* s_src, float* s_dst,
                                              const int* flags) {
    __shared__ short xl[64 * 136];    // [row][k] bf16, padded
    __shared__ short wl[128 * 136];   // [o][k] bf16, padded
    int tid = threadIdx.x;
    int isB = flags[0];
    int nb = blockIdx.x * 64;
    const unsigned short* xu = (const unsigned short*)x;
    const float* xf = (const float*)x;

    #pragma unroll
    for (int it = 0; it < 8; ++it) {
        int o = (tid >> 4) + it * 16;
        int k8 = (tid & 15) * 8;
        *(short8*)&wl[o * 136 + k8] = *(const short8*)&Wbf[o * 128 + k8];
    }
    #pragma unroll
    for (int it = 0; it < 4; ++it) {
        int row = (tid >> 4) + it * 16;
        int k8 = (tid & 15) * 8;
        int node = nb + row;
        short8 val;
        if (node < N_NODES) {
            if (isB) {
                val = *(const short8*)&xu[(size_t)node * 128 + k8];
            } else {
                float4 f0 = *(const float4*)&xf[(size_t)node * 128 + k8];
                float4 f1 = *(const float4*)&xf[(size_t)node * 128 + k8 + 4];
                val[0] = (short)f2bf(f0.x); val[1] = (short)f2bf(f0.y);
                val[2] = (short)f2bf(f0.z); val[3] = (short)f2bf(f0.w);
                val[4] = (short)f2bf(f1.x); val[5] = (short)f2bf(f1.y);
                val[6] = (short)f2bf(f1.z); val[7] = (short)f2bf(f1.w);
            }
        } else {
            val = short8{0,0,0,0,0,0,0,0};
        }
        *(short8*)&xl[row * 136 + k8] = val;
    }
    __syncthreads();

    int wv = tid >> 6, l = tid & 63;
    int lr = l & 15, lg = l >> 4;

    f32x4 acc0 = {0,0,0,0}, acc1 = {0,0,0,0}, acc2 = {0,0,0,0}, acc3 = {0,0,0,0};
    f32x4 acc4 = {0,0,0,0}, acc5 = {0,0,0,0}, acc6 = {0,0,0,0}, acc7 = {0,0,0,0};
    #pragma unroll
    for (int kb = 0; kb < 4; ++kb) {
        short8 a = *(const short8*)&xl[(wv * 16 + lr) * 136 + kb * 32 + lg * 8];
        short8 b0 = *(const short8*)&wl[(0 * 16 + lr) * 136 + kb * 32 + lg * 8];
        short8 b1 = *(const short8*)&wl[(1 * 16 + lr) * 136 + kb * 32 + lg * 8];
        short8 b2 = *(const short8*)&wl[(2 * 16 + lr) * 136 + kb * 32 + lg * 8];
        short8 b3 = *(const short8*)&wl[(3 * 16 + lr) * 136 + kb * 32 + lg * 8];
        short8 b4 = *(const short8*)&wl[(4 * 16 + lr) * 136 + kb * 32 + lg * 8];
        short8 b5 = *(const short8*)&wl[(5 * 16 + lr) * 136 + kb * 32 + lg * 8];
        short8 b6 = *(const short8*)&wl[(6 * 16 + lr) * 136 + kb * 32 + lg * 8];
        short8 b7 = *(const short8*)&wl[(7 * 16 + lr) * 136 + kb * 32 + lg * 8];
        acc0 = __builtin_amdgcn_mfma_f32_16x16x32_bf16(a, b0, acc0, 0, 0, 0);
        acc1 = __builtin_amdgcn_mfma_f32_16x16x32_bf16(a, b1, acc1, 0, 0, 0);
        acc2 = __builtin_amdgcn_mfma_f32_16x16x32_bf16(a, b2, acc2, 0, 0, 0);
        acc3 = __builtin_amdgcn_mfma_f32_16x16x32_bf16(a, b3, acc3, 0, 0, 0);
        acc4 = __builtin_amdgcn_mfma_f32_16x16x32_bf16(a, b4, acc4, 0, 0, 0);
        acc5 = __builtin_amdgcn_mfma_f32_16x16x32_bf16(a, b5, acc5, 0, 0, 0);
        acc6 = __builtin_amdgcn_mfma_f32_16x16x32_bf16(a, b6, acc6, 0, 0, 0);
        acc7 = __builtin_amdgcn_mfma_f32_16x16x32_bf16(a, b7, acc7, 0, 0, 0);
    }

    float pS[4][4], pD[4][4];
    #pragma unroll
    for (int r = 0; r < 4; ++r)
        #pragma unroll
        for (int hd = 0; hd < 4; ++hd) { pS[r][hd] = 0.f; pD[r][hd] = 0.f; }

    #define EPI(OT, ACC) { \
        float aSv = af[(OT) * 16 + lr]; \
        float aDv = af[128 + (OT) * 16 + lr]; \
        _Pragma("unroll") \
        for (int r = 0; r < 4; ++r) { \
            int n = nb + wv * 16 + lg * 4 + r; \
            float v = ACC[r]; \
            if (n < N_NODES) h[(size_t)n * HF + (OT) * 16 + lr] = f2bf(v); \
            pS[r][(OT) >> 1] += v * aSv; \
            pD[r][(OT) >> 1] += v * aDv; \
        } }
    EPI(0, acc0) EPI(1, acc1) EPI(2, acc2) EPI(3, acc3)
    EPI(4, acc4) EPI(5, acc5) EPI(6, acc6) EPI(7, acc7)
    #undef EPI

    #pragma unroll
    for (int off = 1; off < 16; off <<= 1) {
        #pragma unroll
        for (int r = 0; r < 4; ++r)
            #pragma unroll
            for (int hd = 0; hd < 4; ++hd) {
                pS[r][hd] += __shfl_xor(pS[r][hd], off, 64);
                pD[r][hd] += __shfl_xor(pD[r][hd], off, 64);
            }
    }
    if (lr == 0) {
        #pragma unroll
        for (int r = 0; r < 4; ++r) {
            int n = nb + wv * 16 + lg * 4 + r;
            if (n < N_NODES) {
                #pragma unroll
                for (int hd = 0; hd < 4; ++hd) {
                    s_src[n * 4 + hd] = pS[r][hd];
                    s_dst[n * 4 + hd] = pD[r][hd];
                }
            }
        }
    }
}

// ---------- K4a/b/c: coalesced 3-phase exclusive scan ----------
__global__ __launch_bounds__(1024) void k_scan1(const int* counts, int* row_start, int* btot) {
    __shared__ int buf[1024];
    int t = threadIdx.x;
    int i = blockIdx.x * 1024 + t;
    int c = (i < N_NODES) ? counts[i] : 0;
    buf[t] = c;
    __syncthreads();
    for (int off = 1; off < 1024; off <<= 1) {
        int v = (t >= off) ? buf[t - off] : 0;
        __syncthreads();
        buf[t] += v;
        __syncthreads();
    }
    if (i < N_NODES) row_start[i] = buf[t] - c;
    if (t == 1023) btot[blockIdx.x] = buf[1023];
}
__global__ void k_scan2(int* btot, int* row_start, int nblk) {
    int l = threadIdx.x;  // 64 threads
    int v = (l < nblk) ? btot[l] : 0;
    int inc = v;
    for (int off = 1; off < 64; off <<= 1) {
        int u = __shfl_up(inc, off, 64);
        if (l >= off) inc += u;
    }
    int tot = __shfl(inc, nblk - 1, 64);
    if (l < nblk) btot[l] = inc - v;
    if (l == 0) row_start[N_NODES] = tot;
}
__global__ __launch_bounds__(1024) void k_scan3(int* row_start, const int* btot) {
    int i = blockIdx.x * 1024 + threadIdx.x;
    if (i < N_NODES) row_start[i] += btot[blockIdx.x];
}

// ---------- K5: scatter 16B records {src, 4xf16 scores} into CSR slots; 4 edges/thread ----------
__global__ __launch_bounds__(256) void k_scatter(const unsigned int* edgePk, const int* row_start,
                                                 int* cursor, const float* s_src, const float* s_dst,
                                                 uint4* recs) {
    int base = (blockIdx.x * blockDim.x + threadIdx.x) * 4;
    if (base >= N_EDGES) return;
    uint4 ep = *(const uint4*)&edgePk[base];
    unsigned int eps[4] = {ep.x, ep.y, ep.z, ep.w};
    int sA[4], dA[4];
    float4 ssv[4], sdv[4];
    #pragma unroll
    for (int j = 0; j < 4; ++j) {
        sA[j] = (int)(eps[j] & 0xFFFFu);
        dA[j] = (int)(eps[j] >> 16);
        ssv[j] = *(const float4*)&s_src[sA[j] * 4];
        sdv[j] = *(const float4*)&s_dst[dA[j] * 4];
    }
    #pragma unroll
    for (int j = 0; j < 4; ++j) {
        int p = atomicAdd(&cursor[dA[j]], 1);
        int slot = row_start[dA[j]] + p;
        unsigned int q0 = f2h(leaky(ssv[j].x + sdv[j].x));
        unsigned int q1 = f2h(leaky(ssv[j].y + sdv[j].y));
        unsigned int q2 = f2h(leaky(ssv[j].z + sdv[j].z));
        unsigned int q3 = f2h(leaky(ssv[j].w + sdv[j].w));
        uint4 r;
        r.x = (unsigned int)sA[j];
        r.y = q0 | (q1 << 16);
        r.z = q2 | (q3 << 16);
        r.w = 0u;
        recs[slot] = r;
    }
}

// ---------- K6: gather-FMA aggregation with inline softmax (1 wave = 1 node) ----------
// lane split: lf = l&15 (feature octet lf*8..lf*8+7), grp = l>>4 (edge subset), hd = lf>>2.
__global__ __launch_bounds__(256) void k_agg(const unsigned short* h, const uint4* recs,
                                             const int* row_start, float* out) {
    int wid = threadIdx.x >> 6;
    int l = threadIdx.x & 63;
    int n = blockIdx.x * 4 + wid;
    if (n >= N_NODES) return;
    int rs = row_start[n];
    int deg = row_start[n + 1] - rs;
    int lf = l & 15, grp = l >> 4, hd = lf >> 2;
    if (deg == 0) {
        *(float2*)&out[(size_t)n * HF + lf * 8 + grp * 2] = make_float2(0.f, 0.f);
        return;
    }
    const float NI = -__builtin_inff();
    const unsigned int* recW = (const unsigned int*)recs;
    int widx = 1 + (hd >> 1);
    int sh = (hd & 1) * 16;

    // pass 1: per-head segment max from stored f16 scores (dword reads, 2 shuffles)
    float m = NI;
    for (int e = grp; e < deg; e += 4) {
        unsigned int w = recW[(size_t)(rs + e) * 4 + widx];
        m = fmaxf(m, h2f((unsigned short)(w >> sh)));
    }
    m = fmaxf(m, __shfl_xor(m, 16, 64));
    m = fmaxf(m, __shfl_xor(m, 32, 64));

    // pass 2: gather h, weight by exp(s-m), accumulate z and unnormalized out
    float z = 0.f;
    float a0=0,a1=0,a2=0,a3=0,a4=0,a5=0,a6=0,a7=0;
    float sc = NI; int si = 0;
    if (grp < deg) {
        uint4 r = recs[rs + grp];
        si = (int)r.x;
        sc = h2f((unsigned short)((((hd & 2) ? r.z : r.y)) >> sh));
    }
    uint4 u = *(const uint4*)&h[(size_t)si * HF + lf * 8];

    for (int it = 0; it < deg; it += 4) {
        int e1 = it + 4 + grp;
        float sc1 = NI; int si1 = 0;
        if (e1 < deg) {
            uint4 r = recs[rs + e1];
            si1 = (int)r.x;
            sc1 = h2f((unsigned short)((((hd & 2) ? r.z : r.y)) >> sh));
        }
        uint4 u1 = *(const uint4*)&h[(size_t)si1 * HF + lf * 8];
        float w = __expf(sc - m);          // 0 for invalid slots (sc = -inf)
        z += w;
        a0 += w * bf2f((unsigned short)(u.x & 0xFFFFu)); a1 += w * bf2f((unsigned short)(u.x >> 16));
        a2 += w * bf2f((unsigned short)(u.y & 0xFFFFu)); a3 += w * bf2f((unsigned short)(u.y >> 16));
        a4 += w * bf2f((unsigned short)(u.z & 0xFFFFu)); a5 += w * bf2f((unsigned short)(u.z >> 16));
        a6 += w * bf2f((unsigned short)(u.w & 0xFFFFu)); a7 += w * bf2f((unsigned short)(u.w >> 16));
        sc = sc1; si = si1; u = u1;
    }
    // reduce z and acc across the 4 edge-groups (lane bits 4,5)
    #pragma unroll
    for (int off = 16; off <= 32; off <<= 1) {
        z  += __shfl_xor(z,  off, 64);
        a0 += __shfl_xor(a0, off, 64); a1 += __shfl_xor(a1, off, 64);
        a2 += __shfl_xor(a2, off, 64); a3 += __shfl_xor(a3, off, 64);
        a4 += __shfl_xor(a4, off, 64); a5 += __shfl_xor(a5, off, 64);
        a6 += __shfl_xor(a6, off, 64); a7 += __shfl_xor(a7, off, 64);
    }
    float inv = 1.0f / (z + EPS_F);
    if (grp == 0) *(float4*)&out[(size_t)n * HF + lf * 8]     = make_float4(a0*inv, a1*inv, a2*inv, a3*inv);
    if (grp == 1) *(float4*)&out[(size_t)n * HF + lf * 8 + 4] = make_float4(a4*inv, a5*inv, a6*inv, a7*inv);
}

extern "C" void kernel_launch(void* const* d_in, const int* in_sizes, int n_in,
                              void* d_out, int out_size, void* d_ws, size_t ws_size,
                              hipStream_t stream) {
    const void* x     = d_in[0];
    const void* eidx  = d_in[1];
    const void* W     = d_in[2];
    const void* a_src = d_in[3];
    const void* a_dst = d_in[4];
    char* ws = (char*)d_ws;

    size_t off = 0;
    auto alloc = [&](size_t bytes) { size_t o = off; off += (bytes + 255) & ~(size_t)255; return o; };
    size_t flagsO  = alloc(64 * 4);
    size_t countsO = alloc((size_t)N_NODES * 4);
    size_t cursorO = alloc((size_t)N_NODES * 4);
    size_t zeroEnd = off;                       // [countsO, zeroEnd) memset 0
    size_t rowO    = alloc((size_t)(N_NODES + 1) * 4);
    size_t btotO   = alloc(64 * 4);
    size_t epkO    = alloc((size_t)N_EDGES * 4);
    size_t recsO   = alloc((size_t)N_EDGES * 16);
    size_t WbO     = alloc(16384 * 2);
    size_t afO     = alloc(256 * 4);
    size_t ssO     = alloc((size_t)N_NODES * 4 * 4);
    size_t sdO     = alloc((size_t)N_NODES * 4 * 4);
    size_t hO      = alloc((size_t)N_NODES * HF * 2);
    (void)ws_size; (void)in_sizes; (void)n_in;

    int*   flags   = (int*)(ws + flagsO);
    int*   counts  = (int*)(ws + countsO);
    int*   cursor  = (int*)(ws + cursorO);
    int*   rowSt   = (int*)(ws + rowO);
    int*   btot    = (int*)(ws + btotO);
    unsigned int* edgePk = (unsigned int*)(ws + epkO);
    uint4* recs    = (uint4*)(ws + recsO);
    unsigned short* Wbf = (unsigned short*)(ws + WbO);
    float* af      = (float*)(ws + afO);
    float* s_src   = (float*)(ws + ssO);
    float* s_dst   = (float*)(ws + sdO);
    unsigned short* h = (unsigned short*)(ws + hO);
    float* outF    = (float*)d_out;

    hipMemsetAsync(ws + countsO, 0, zeroEnd - countsO, stream);

    const int SCAN_BLKS = (N_NODES + 1023) / 1024;   // 49
    k_sniff<<<1, 64, 0, stream>>>(x, eidx, flags);
    k_convert<<<(N_EDGES + 255) / 256, 256, 0, stream>>>(W, a_src, a_dst, eidx, Wbf, af, edgePk, counts, flags);
    k_gemm<<<(N_NODES + 63) / 64, 256, 0, stream>>>(x, Wbf, af, h, s_src, s_dst, flags);
    k_scan1<<<SCAN_BLKS, 1024, 0, stream>>>(counts, rowSt, btot);
    k_scan2<<<1, 64, 0, stream>>>(btot, rowSt, SCAN_BLKS);
    k_scan3<<<SCAN_BLKS, 1024, 0, stream>>>(rowSt, btot);
    k_scatter<<<(N_EDGES / 4 + 255) / 256, 256, 0, stream>>>(edgePk, rowSt, cursor, s_src, s_dst, recs);
    k_agg<<<(N_NODES + 3) / 4, 256, 0, stream>>>(h, recs, rowSt, outF);
}

// Round 8
// 212.929 us; speedup vs baseline: 1.0591x; 1.0591x over previous
//
#include <hip/hip_runtime.h>
#include <stdint.h>

#define N_NODES 50000
#define N_EDGES 800000
#define HF 128          // HEADS * OUT_F
#define NEG_SLOPE 0.2f
#define EPS_F 1e-8f
#define NBKT 196        // buckets = dst>>8, dst<50000 -> 0..195
#define NBLK 256        // blocks in hist/bucket1 passes
#define EPB (N_EDGES / NBLK)   // 3125, exact

typedef __attribute__((ext_vector_type(8))) short short8;
typedef __attribute__((ext_vector_type(4))) float f32x4;

// ---------- helpers ----------
__device__ __forceinline__ float bf2f(unsigned short u) {
    union { unsigned int i; float f; } v; v.i = ((unsigned int)u) << 16; return v.f;
}
__device__ __forceinline__ unsigned short f2bf(float f) {
    union { unsigned int i; float f; } v; v.f = f;
    unsigned int b = v.i;
    unsigned int r = (b + 0x7FFFu + ((b >> 16) & 1u)) >> 16;   // round-to-nearest-even
    return (unsigned short)r;
}
__device__ __forceinline__ float leaky(float v) { return v > 0.f ? v : NEG_SLOPE * v; }
__device__ __forceinline__ unsigned short f2h(float f) {
    _Float16 h = (_Float16)f; unsigned short u; __builtin_memcpy(&u, &h, 2); return u;
}
__device__ __forceinline__ float h2f(unsigned short u) {
    _Float16 h; __builtin_memcpy(&h, &u, 2); return (float)h;
}

// ---------- K0: dtype sniff ----------
__global__ void k_sniff(const void* x, const void* eidx, int* flags) {
    int l = threadIdx.x;  // 64 threads
    const unsigned short* xu = (const unsigned short*)x;
    float f = bf2f(xu[2 * l]);
    float af = fabsf(f);
    bool extreme = !(af <= 1e6f) || (f != 0.0f && af < 1e-7f);
    unsigned long long mask = __ballot(extreme);
    const unsigned int* eu = (const unsigned int*)eidx;
    unsigned int w = eu[2 * l + 1];
    unsigned long long mask2 = __ballot(w != 0u);
    if (l == 0) {
        flags[0] = (__popcll(mask) >= 8) ? 0 : 1;   // 1 = bf16 floats
        flags[1] = (__popcll(mask2) >= 4) ? 0 : 1;  // 1 = int64 indices
    }
}

// ---------- K1: normalize W->bf16, a->f32, edges->packed u32 (src|dst<<16), degree count ----------
__global__ void k_convert(const void* W, const void* a_src, const void* a_dst, const void* eidx,
                          unsigned short* Wbf, float* af, unsigned int* edgePk, int* counts,
                          const int* flags) {
    int i = blockIdx.x * blockDim.x + threadIdx.x;
    int isB = flags[0], is64 = flags[1];
    if (i < 16384) Wbf[i] = isB ? ((const unsigned short*)W)[i] : f2bf(((const float*)W)[i]);
    if (i < 128) {
        af[i]       = isB ? bf2f(((const unsigned short*)a_src)[i]) : ((const float*)a_src)[i];
        af[128 + i] = isB ? bf2f(((const unsigned short*)a_dst)[i]) : ((const float*)a_dst)[i];
    }
    if (i < N_EDGES) {
        int s, d;
        if (is64) {
            s = (int)((const long long*)eidx)[i];
            d = (int)((const long long*)eidx)[N_EDGES + i];
        } else {
            s = ((const int*)eidx)[i];
            d = ((const int*)eidx)[N_EDGES + i];
        }
        edgePk[i] = (unsigned int)s | ((unsigned int)d << 16);
        atomicAdd(&counts[d], 1);          // no-return atomic: fast
    }
}

// ---------- K2: MFMA GEMM  h = x @ W^T (bf16), fused scores s_src/s_dst ----------
__global__ __launch_bounds__(256) void k_gemm(const void* x, const unsigned short* Wbf, const float* af,
                                              unsigned short* h, float* s_src, float* s_dst,
                                              const int* flags) {
    __shared__ short xl[64 * 136];    // [row][k] bf16, padded
    __shared__ short wl[128 * 136];   // [o][k] bf16, padded
    int tid = threadIdx.x;
    int isB = flags[0];
    int nb = blockIdx.x * 64;
    const unsigned short* xu = (const unsigned short*)x;
    const float* xf = (const float*)x;

    #pragma unroll
    for (int it = 0; it < 8; ++it) {
        int o = (tid >> 4) + it * 16;
        int k8 = (tid & 15) * 8;
        *(short8*)&wl[o * 136 + k8] = *(const short8*)&Wbf[o * 128 + k8];
    }
    #pragma unroll
    for (int it = 0; it < 4; ++it) {
        int row = (tid >> 4) + it * 16;
        int k8 = (tid & 15) * 8;
        int node = nb + row;
        short8 val;
        if (node < N_NODES) {
            if (isB) {
                val = *(const short8*)&xu[(size_t)node * 128 + k8];
            } else {
                float4 f0 = *(const float4*)&xf[(size_t)node * 128 + k8];
                float4 f1 = *(const float4*)&xf[(size_t)node * 128 + k8 + 4];
                val[0] = (short)f2bf(f0.x); val[1] = (short)f2bf(f0.y);
                val[2] = (short)f2bf(f0.z); val[3] = (short)f2bf(f0.w);
                val[4] = (short)f2bf(f1.x); val[5] = (short)f2bf(f1.y);
                val[6] = (short)f2bf(f1.z); val[7] = (short)f2bf(f1.w);
            }
        } else {
            val = short8{0,0,0,0,0,0,0,0};
        }
        *(short8*)&xl[row * 136 + k8] = val;
    }
    __syncthreads();

    int wv = tid >> 6, l = tid & 63;
    int lr = l & 15, lg = l >> 4;

    f32x4 acc0 = {0,0,0,0}, acc1 = {0,0,0,0}, acc2 = {0,0,0,0}, acc3 = {0,0,0,0};
    f32x4 acc4 = {0,0,0,0}, acc5 = {0,0,0,0}, acc6 = {0,0,0,0}, acc7 = {0,0,0,0};
    #pragma unroll
    for (int kb = 0; kb < 4; ++kb) {
        short8 a = *(const short8*)&xl[(wv * 16 + lr) * 136 + kb * 32 + lg * 8];
        short8 b0 = *(const short8*)&wl[(0 * 16 + lr) * 136 + kb * 32 + lg * 8];
        short8 b1 = *(const short8*)&wl[(1 * 16 + lr) * 136 + kb * 32 + lg * 8];
        short8 b2 = *(const short8*)&wl[(2 * 16 + lr) * 136 + kb * 32 + lg * 8];
        short8 b3 = *(const short8*)&wl[(3 * 16 + lr) * 136 + kb * 32 + lg * 8];
        short8 b4 = *(const short8*)&wl[(4 * 16 + lr) * 136 + kb * 32 + lg * 8];
        short8 b5 = *(const short8*)&wl[(5 * 16 + lr) * 136 + kb * 32 + lg * 8];
        short8 b6 = *(const short8*)&wl[(6 * 16 + lr) * 136 + kb * 32 + lg * 8];
        short8 b7 = *(const short8*)&wl[(7 * 16 + lr) * 136 + kb * 32 + lg * 8];
        acc0 = __builtin_amdgcn_mfma_f32_16x16x32_bf16(a, b0, acc0, 0, 0, 0);
        acc1 = __builtin_amdgcn_mfma_f32_16x16x32_bf16(a, b1, acc1, 0, 0, 0);
        acc2 = __builtin_amdgcn_mfma_f32_16x16x32_bf16(a, b2, acc2, 0, 0, 0);
        acc3 = __builtin_amdgcn_mfma_f32_16x16x32_bf16(a, b3, acc3, 0, 0, 0);
        acc4 = __builtin_amdgcn_mfma_f32_16x16x32_bf16(a, b4, acc4, 0, 0, 0);
        acc5 = __builtin_amdgcn_mfma_f32_16x16x32_bf16(a, b5, acc5, 0, 0, 0);
        acc6 = __builtin_amdgcn_mfma_f32_16x16x32_bf16(a, b6, acc6, 0, 0, 0);
        acc7 = __builtin_amdgcn_mfma_f32_16x16x32_bf16(a, b7, acc7, 0, 0, 0);
    }

    float pS[4][4], pD[4][4];
    #pragma unroll
    for (int r = 0; r < 4; ++r)
        #pragma unroll
        for (int hd = 0; hd < 4; ++hd) { pS[r][hd] = 0.f; pD[r][hd] = 0.f; }

    #define EPI(OT, ACC) { \
        float aSv = af[(OT) * 16 + lr]; \
        float aDv = af[128 + (OT) * 16 + lr]; \
        _Pragma("unroll") \
        for (int r = 0; r < 4; ++r) { \
            int n = nb + wv * 16 + lg * 4 + r; \
            float v = ACC[r]; \
            if (n < N_NODES) h[(size_t)n * HF + (OT) * 16 + lr] = f2bf(v); \
            pS[r][(OT) >> 1] += v * aSv; \
            pD[r][(OT) >> 1] += v * aDv; \
        } }
    EPI(0, acc0) EPI(1, acc1) EPI(2, acc2) EPI(3, acc3)
    EPI(4, acc4) EPI(5, acc5) EPI(6, acc6) EPI(7, acc7)
    #undef EPI

    #pragma unroll
    for (int off = 1; off < 16; off <<= 1) {
        #pragma unroll
        for (int r = 0; r < 4; ++r)
            #pragma unroll
            for (int hd = 0; hd < 4; ++hd) {
                pS[r][hd] += __shfl_xor(pS[r][hd], off, 64);
                pD[r][hd] += __shfl_xor(pD[r][hd], off, 64);
            }
    }
    if (lr == 0) {
        #pragma unroll
        for (int r = 0; r < 4; ++r) {
            int n = nb + wv * 16 + lg * 4 + r;
            if (n < N_NODES) {
                #pragma unroll
                for (int hd = 0; hd < 4; ++hd) {
                    s_src[n * 4 + hd] = pS[r][hd];
                    s_dst[n * 4 + hd] = pD[r][hd];
                }
            }
        }
    }
}

// ---------- scan kernels (parameterized length; exclusive scan of counts -> offsets) ----------
__global__ __launch_bounds__(1024) void k_scan1(const int* counts, int* offs, int* btot, int n) {
    __shared__ int buf[1024];
    int t = threadIdx.x;
    int i = blockIdx.x * 1024 + t;
    int c = (i < n) ? counts[i] : 0;
    buf[t] = c;
    __syncthreads();
    for (int off = 1; off < 1024; off <<= 1) {
        int v = (t >= off) ? buf[t - off] : 0;
        __syncthreads();
        buf[t] += v;
        __syncthreads();
    }
    if (i < n) offs[i] = buf[t] - c;
    if (t == 1023) btot[blockIdx.x] = buf[1023];
}
__global__ void k_scan2(int* btot, int* offs, int nblk, int n) {
    int l = threadIdx.x;  // 64 threads
    int v = (l < nblk) ? btot[l] : 0;
    int inc = v;
    for (int off = 1; off < 64; off <<= 1) {
        int u = __shfl_up(inc, off, 64);
        if (l >= off) inc += u;
    }
    int tot = __shfl(inc, nblk - 1, 64);
    if (l < nblk) btot[l] = inc - v;
    if (l == 0) offs[n] = tot;
}
__global__ __launch_bounds__(1024) void k_scan3(int* offs, const int* btot, int n) {
    int i = blockIdx.x * 1024 + threadIdx.x;
    if (i < n) offs[i] += btot[blockIdx.x];
}

// ---------- K5a: per-block bucket histogram (bucket = dst>>8 = pk>>24) ----------
__global__ __launch_bounds__(256) void k_hist1(const unsigned int* edgePk, int* bh) {
    __shared__ int lh[NBKT];
    int tid = threadIdx.x, blk = blockIdx.x;
    if (tid < NBKT) lh[tid] = 0;
    __syncthreads();
    int e0 = blk * EPB;
    for (int i = tid; i < EPB; i += 256)
        atomicAdd(&lh[edgePk[e0 + i] >> 24], 1);      // LDS atomic
    __syncthreads();
    if (tid < NBKT) bh[tid * NBLK + blk] = lh[tid];   // bucket-major
}

// ---------- K5b: scatter edges into bucket-major order (LDS returning atomics only) ----------
__global__ __launch_bounds__(256) void k_bucket1(const unsigned int* edgePk, const int* base,
                                                 unsigned int* bkt) {
    __shared__ int lcur[NBKT];
    int tid = threadIdx.x, blk = blockIdx.x;
    if (tid < NBKT) lcur[tid] = base[tid * NBLK + blk];
    __syncthreads();
    int e0 = blk * EPB;
    for (int i = tid; i < EPB; i += 256) {
        unsigned int pk = edgePk[e0 + i];
        int slot = atomicAdd(&lcur[pk >> 24], 1);     // LDS returning atomic: fast
        bkt[slot] = pk;
    }
}

// ---------- K5c: one block per bucket -> final CSR records {src, 4xf16 scores} ----------
__global__ __launch_bounds__(256) void k_bucket2(const unsigned int* bkt, const int* base,
                                                 const int* row_start, const float* s_src,
                                                 const float* s_dst, uint4* recs) {
    __shared__ int lcur[256];
    int tid = threadIdx.x, bk = blockIdx.x;
    lcur[tid] = 0;
    __syncthreads();
    int bstart = base[bk * NBLK];
    int bend   = base[(bk + 1) * NBLK];   // bk=195 -> base[50176] = total
    for (int i = bstart + tid; i < bend; i += 256) {
        unsigned int pk = bkt[i];
        int s = (int)(pk & 0xFFFFu), d = (int)(pk >> 16);
        int r = atomicAdd(&lcur[d & 255], 1);         // LDS returning atomic
        int slot = row_start[d] + r;
        float4 ss = *(const float4*)&s_src[s * 4];
        float4 sd = *(const float4*)&s_dst[d * 4];
        unsigned int q0 = f2h(leaky(ss.x + sd.x));
        unsigned int q1 = f2h(leaky(ss.y + sd.y));
        unsigned int q2 = f2h(leaky(ss.z + sd.z));
        unsigned int q3 = f2h(leaky(ss.w + sd.w));
        uint4 rc;
        rc.x = (unsigned int)s;
        rc.y = q0 | (q1 << 16);
        rc.z = q2 | (q3 << 16);
        rc.w = 0u;
        recs[slot] = rc;                               // region-local write (bucket-owned)
    }
}

// ---------- K6: gather-FMA aggregation with inline softmax (1 wave = 1 node) ----------
__global__ __launch_bounds__(256) void k_agg(const unsigned short* h, const uint4* recs,
                                             const int* row_start, float* out) {
    int wid = threadIdx.x >> 6;
    int l = threadIdx.x & 63;
    int n = blockIdx.x * 4 + wid;
    if (n >= N_NODES) return;
    int rs = row_start[n];
    int deg = row_start[n + 1] - rs;
    int lf = l & 15, grp = l >> 4, hd = lf >> 2;
    if (deg == 0) {
        *(float2*)&out[(size_t)n * HF + lf * 8 + grp * 2] = make_float2(0.f, 0.f);
        return;
    }
    const float NI = -__builtin_inff();
    const unsigned int* recW = (const unsigned int*)recs;
    int widx = 1 + (hd >> 1);
    int sh = (hd & 1) * 16;

    // pass 1: per-head segment max from stored f16 scores
    float m = NI;
    for (int e = grp; e < deg; e += 4) {
        unsigned int w = recW[(size_t)(rs + e) * 4 + widx];
        m = fmaxf(m, h2f((unsigned short)(w >> sh)));
    }
    m = fmaxf(m, __shfl_xor(m, 16, 64));
    m = fmaxf(m, __shfl_xor(m, 32, 64));

    // pass 2: gather h, weight by exp(s-m), accumulate z and unnormalized out
    float z = 0.f;
    float a0=0,a1=0,a2=0,a3=0,a4=0,a5=0,a6=0,a7=0;
    float sc = NI; int si = 0;
    if (grp < deg) {
        uint4 r = recs[rs + grp];
        si = (int)r.x;
        sc = h2f((unsigned short)((((hd & 2) ? r.z : r.y)) >> sh));
    }
    uint4 u = *(const uint4*)&h[(size_t)si * HF + lf * 8];

    for (int it = 0; it < deg; it += 4) {
        int e1 = it + 4 + grp;
        float sc1 = NI; int si1 = 0;
        if (e1 < deg) {
            uint4 r = recs[rs + e1];
            si1 = (int)r.x;
            sc1 = h2f((unsigned short)((((hd & 2) ? r.z : r.y)) >> sh));
        }
        uint4 u1 = *(const uint4*)&h[(size_t)si1 * HF + lf * 8];
        float w = __expf(sc - m);          // 0 for invalid slots (sc = -inf)
        z += w;
        a0 += w * bf2f((unsigned short)(u.x & 0xFFFFu)); a1 += w * bf2f((unsigned short)(u.x >> 16));
        a2 += w * bf2f((unsigned short)(u.y & 0xFFFFu)); a3 += w * bf2f((unsigned short)(u.y >> 16));
        a4 += w * bf2f((unsigned short)(u.z & 0xFFFFu)); a5 += w * bf2f((unsigned short)(u.z >> 16));
        a6 += w * bf2f((unsigned short)(u.w & 0xFFFFu)); a7 += w * bf2f((unsigned short)(u.w >> 16));
        sc = sc1; si = si1; u = u1;
    }
    #pragma unroll
    for (int off = 16; off <= 32; off <<= 1) {
        z  += __shfl_xor(z,  off, 64);
        a0 += __shfl_xor(a0, off, 64); a1 += __shfl_xor(a1, off, 64);
        a2 += __shfl_xor(a2, off, 64); a3 += __shfl_xor(a3, off, 64);
        a4 += __shfl_xor(a4, off, 64); a5 += __shfl_xor(a5, off, 64);
        a6 += __shfl_xor(a6, off, 64); a7 += __shfl_xor(a7, off, 64);
    }
    float inv = 1.0f / (z + EPS_F);
    if (grp == 0) *(float4*)&out[(size_t)n * HF + lf * 8]     = make_float4(a0*inv, a1*inv, a2*inv, a3*inv);
    if (grp == 1) *(float4*)&out[(size_t)n * HF + lf * 8 + 4] = make_float4(a4*inv, a5*inv, a6*inv, a7*inv);
}

extern "C" void kernel_launch(void* const* d_in, const int* in_sizes, int n_in,
                              void* d_out, int out_size, void* d_ws, size_t ws_size,
                              hipStream_t stream) {
    const void* x     = d_in[0];
    const void* eidx  = d_in[1];
    const void* W     = d_in[2];
    const void* a_src = d_in[3];
    const void* a_dst = d_in[4];
    char* ws = (char*)d_ws;

    size_t off = 0;
    auto alloc = [&](size_t bytes) { size_t o = off; off += (bytes + 255) & ~(size_t)255; return o; };
    size_t flagsO  = alloc(64 * 4);
    size_t countsO = alloc((size_t)N_NODES * 4);
    size_t zeroEnd = off;                       // [countsO, zeroEnd) memset 0
    size_t rowO    = alloc((size_t)(N_NODES + 1) * 4);
    size_t btotO   = alloc(64 * 4);
    size_t btot2O  = alloc(64 * 4);
    size_t bhO     = alloc((size_t)NBKT * NBLK * 4);
    size_t baseO   = alloc((size_t)(NBKT * NBLK + 1) * 4);
    size_t epkO    = alloc((size_t)N_EDGES * 4);
    size_t bktO    = alloc((size_t)N_EDGES * 4);
    size_t recsO   = alloc((size_t)N_EDGES * 16);
    size_t WbO     = alloc(16384 * 2);
    size_t afO     = alloc(256 * 4);
    size_t ssO     = alloc((size_t)N_NODES * 4 * 4);
    size_t sdO     = alloc((size_t)N_NODES * 4 * 4);
    size_t hO      = alloc((size_t)N_NODES * HF * 2);
    (void)ws_size; (void)in_sizes; (void)n_in;

    int*   flags   = (int*)(ws + flagsO);
    int*   counts  = (int*)(ws + countsO);
    int*   rowSt   = (int*)(ws + rowO);
    int*   btot    = (int*)(ws + btotO);
    int*   btot2   = (int*)(ws + btot2O);
    int*   bh      = (int*)(ws + bhO);
    int*   base    = (int*)(ws + baseO);
    unsigned int* edgePk = (unsigned int*)(ws + epkO);
    unsigned int* bkt    = (unsigned int*)(ws + bktO);
    uint4* recs    = (uint4*)(ws + recsO);
    unsigned short* Wbf = (unsigned short*)(ws + WbO);
    float* af      = (float*)(ws + afO);
    float* s_src   = (float*)(ws + ssO);
    float* s_dst   = (float*)(ws + sdO);
    unsigned short* h = (unsigned short*)(ws + hO);
    float* outF    = (float*)d_out;

    hipMemsetAsync(ws + countsO, 0, zeroEnd - countsO, stream);

    const int NODE_SCAN_BLKS = (N_NODES + 1023) / 1024;         // 49
    const int BKT_N = NBKT * NBLK;                              // 50176
    const int BKT_SCAN_BLKS = (BKT_N + 1023) / 1024;            // 49

    k_sniff<<<1, 64, 0, stream>>>(x, eidx, flags);
    k_convert<<<(N_EDGES + 255) / 256, 256, 0, stream>>>(W, a_src, a_dst, eidx, Wbf, af, edgePk, counts, flags);
    k_gemm<<<(N_NODES + 63) / 64, 256, 0, stream>>>(x, Wbf, af, h, s_src, s_dst, flags);
    // node-degree scan -> row_start
    k_scan1<<<NODE_SCAN_BLKS, 1024, 0, stream>>>(counts, rowSt, btot, N_NODES);
    k_scan2<<<1, 64, 0, stream>>>(btot, rowSt, NODE_SCAN_BLKS, N_NODES);
    k_scan3<<<NODE_SCAN_BLKS, 1024, 0, stream>>>(rowSt, btot, N_NODES);
    // bucket grouping (no global returning atomics)
    k_hist1<<<NBLK, 256, 0, stream>>>(edgePk, bh);
    k_scan1<<<BKT_SCAN_BLKS, 1024, 0, stream>>>(bh, base, btot2, BKT_N);
    k_scan2<<<1, 64, 0, stream>>>(btot2, base, BKT_SCAN_BLKS, BKT_N);
    k_scan3<<<BKT_SCAN_BLKS, 1024, 0, stream>>>(base, btot2, BKT_N);
    k_bucket1<<<NBLK, 256, 0, stream>>>(edgePk, base, bkt);
    k_bucket2<<<NBKT, 256, 0, stream>>>(bkt, base, rowSt, s_src, s_dst, recs);
    k_agg<<<(N_NODES + 3) / 4, 256, 0, stream>>>(h, recs, rowSt, outF);
}

// Round 9
// 195.219 us; speedup vs baseline: 1.1552x; 1.0907x over previous
//
#include <hip/hip_runtime.h>
#include <stdint.h>

#define N_NODES 50000
#define N_EDGES 800000
#define HF 128          // HEADS * OUT_F
#define NEG_SLOPE 0.2f
#define EPS_F 1e-8f
#define NBKT 196        // buckets = dst>>8, dst<50000 -> 0..195
#define NBLK 256        // blocks in convert/bucket1 passes
#define EPB (N_EDGES / NBLK)   // 3125, exact
#define BKT_N (NBKT * NBLK)    // 50176
#define SCAN_A 49              // blocks for node scan  (49*1024 >= 50000)
#define SCAN_B 49              // blocks for bucket scan (49*1024 == 50176)

typedef __attribute__((ext_vector_type(8))) short short8;
typedef __attribute__((ext_vector_type(4))) float f32x4;

// ---------- helpers ----------
__device__ __forceinline__ float bf2f(unsigned short u) {
    union { unsigned int i; float f; } v; v.i = ((unsigned int)u) << 16; return v.f;
}
__device__ __forceinline__ unsigned short f2bf(float f) {
    union { unsigned int i; float f; } v; v.f = f;
    unsigned int b = v.i;
    unsigned int r = (b + 0x7FFFu + ((b >> 16) & 1u)) >> 16;   // round-to-nearest-even
    return (unsigned short)r;
}
__device__ __forceinline__ float leaky(float v) { return v > 0.f ? v : NEG_SLOPE * v; }
__device__ __forceinline__ unsigned short f2h(float f) {
    _Float16 h = (_Float16)f; unsigned short u; __builtin_memcpy(&u, &h, 2); return u;
}
__device__ __forceinline__ float h2f(unsigned short u) {
    _Float16 h; __builtin_memcpy(&h, &u, 2); return (float)h;
}

// ---------- K0: dtype sniff ----------
__global__ void k_sniff(const void* x, const void* eidx, int* flags) {
    int l = threadIdx.x;  // 64 threads
    const unsigned short* xu = (const unsigned short*)x;
    float f = bf2f(xu[2 * l]);
    float af = fabsf(f);
    bool extreme = !(af <= 1e6f) || (f != 0.0f && af < 1e-7f);
    unsigned long long mask = __ballot(extreme);
    const unsigned int* eu = (const unsigned int*)eidx;
    unsigned int w = eu[2 * l + 1];
    unsigned long long mask2 = __ballot(w != 0u);
    if (l == 0) {
        flags[0] = (__popcll(mask) >= 8) ? 0 : 1;   // 1 = bf16 floats
        flags[1] = (__popcll(mask2) >= 4) ? 0 : 1;  // 1 = int64 indices
    }
}

// ---------- K1: convert W/a, pack edges, degree count, fused bucket histogram ----------
// 256 blocks x 256 threads. blocks 0..63 also convert W; block 64 converts a_src/a_dst.
__global__ __launch_bounds__(256) void k_convert(const void* W, const void* a_src, const void* a_dst,
                                                 const void* eidx, unsigned short* Wbf, float* af,
                                                 unsigned int* edgePk, int* counts, int* bh,
                                                 const int* flags) {
    __shared__ int lh[NBKT];
    int tid = threadIdx.x, blk = blockIdx.x;
    int isB = flags[0], is64 = flags[1];
    if (tid < NBKT) lh[tid] = 0;
    if (blk < 64) {
        int i = blk * 256 + tid;   // 16384 W elements
        Wbf[i] = isB ? ((const unsigned short*)W)[i] : f2bf(((const float*)W)[i]);
    } else if (blk == 64 && tid < 128) {
        af[tid]       = isB ? bf2f(((const unsigned short*)a_src)[tid]) : ((const float*)a_src)[tid];
        af[128 + tid] = isB ? bf2f(((const unsigned short*)a_dst)[tid]) : ((const float*)a_dst)[tid];
    }
    __syncthreads();
    int e0 = blk * EPB;
    for (int i = tid; i < EPB; i += 256) {
        int e = e0 + i;
        int s, d;
        if (is64) {
            s = (int)((const long long*)eidx)[e];
            d = (int)((const long long*)eidx)[N_EDGES + e];
        } else {
            s = ((const int*)eidx)[e];
            d = ((const int*)eidx)[N_EDGES + e];
        }
        edgePk[e] = (unsigned int)s | ((unsigned int)d << 16);
        atomicAdd(&counts[d], 1);     // no-return global atomic (fast path)
        atomicAdd(&lh[d >> 8], 1);    // LDS histogram
    }
    __syncthreads();
    if (tid < NBKT) bh[tid * NBLK + blk] = lh[tid];   // bucket-major
}

// ---------- K2: MFMA GEMM  h = x @ W^T (bf16), fused scores s_src/s_dst ----------
__global__ __launch_bounds__(256) void k_gemm(const void* x, const unsigned short* Wbf, const float* af,
                                              unsigned short* h, float* s_src, float* s_dst,
                                              const int* flags) {
    __shared__ short xl[64 * 136];    // [row][k] bf16, padded
    __shared__ short wl[128 * 136];   // [o][k] bf16, padded
    int tid = threadIdx.x;
    int isB = flags[0];
    int nb = blockIdx.x * 64;
    const unsigned short* xu = (const unsigned short*)x;
    const float* xf = (const float*)x;

    #pragma unroll
    for (int it = 0; it < 8; ++it) {
        int o = (tid >> 4) + it * 16;
        int k8 = (tid & 15) * 8;
        *(short8*)&wl[o * 136 + k8] = *(const short8*)&Wbf[o * 128 + k8];
    }
    #pragma unroll
    for (int it = 0; it < 4; ++it) {
        int row = (tid >> 4) + it * 16;
        int k8 = (tid & 15) * 8;
        int node = nb + row;
        short8 val;
        if (node < N_NODES) {
            if (isB) {
                val = *(const short8*)&xu[(size_t)node * 128 + k8];
            } else {
                float4 f0 = *(const float4*)&xf[(size_t)node * 128 + k8];
                float4 f1 = *(const float4*)&xf[(size_t)node * 128 + k8 + 4];
                val[0] = (short)f2bf(f0.x); val[1] = (short)f2bf(f0.y);
                val[2] = (short)f2bf(f0.z); val[3] = (short)f2bf(f0.w);
                val[4] = (short)f2bf(f1.x); val[5] = (short)f2bf(f1.y);
                val[6] = (short)f2bf(f1.z); val[7] = (short)f2bf(f1.w);
            }
        } else {
            val = short8{0,0,0,0,0,0,0,0};
        }
        *(short8*)&xl[row * 136 + k8] = val;
    }
    __syncthreads();

    int wv = tid >> 6, l = tid & 63;
    int lr = l & 15, lg = l >> 4;

    f32x4 acc0 = {0,0,0,0}, acc1 = {0,0,0,0}, acc2 = {0,0,0,0}, acc3 = {0,0,0,0};
    f32x4 acc4 = {0,0,0,0}, acc5 = {0,0,0,0}, acc6 = {0,0,0,0}, acc7 = {0,0,0,0};
    #pragma unroll
    for (int kb = 0; kb < 4; ++kb) {
        short8 a = *(const short8*)&xl[(wv * 16 + lr) * 136 + kb * 32 + lg * 8];
        short8 b0 = *(const short8*)&wl[(0 * 16 + lr) * 136 + kb * 32 + lg * 8];
        short8 b1 = *(const short8*)&wl[(1 * 16 + lr) * 136 + kb * 32 + lg * 8];
        short8 b2 = *(const short8*)&wl[(2 * 16 + lr) * 136 + kb * 32 + lg * 8];
        short8 b3 = *(const short8*)&wl[(3 * 16 + lr) * 136 + kb * 32 + lg * 8];
        short8 b4 = *(const short8*)&wl[(4 * 16 + lr) * 136 + kb * 32 + lg * 8];
        short8 b5 = *(const short8*)&wl[(5 * 16 + lr) * 136 + kb * 32 + lg * 8];
        short8 b6 = *(const short8*)&wl[(6 * 16 + lr) * 136 + kb * 32 + lg * 8];
        short8 b7 = *(const short8*)&wl[(7 * 16 + lr) * 136 + kb * 32 + lg * 8];
        acc0 = __builtin_amdgcn_mfma_f32_16x16x32_bf16(a, b0, acc0, 0, 0, 0);
        acc1 = __builtin_amdgcn_mfma_f32_16x16x32_bf16(a, b1, acc1, 0, 0, 0);
        acc2 = __builtin_amdgcn_mfma_f32_16x16x32_bf16(a, b2, acc2, 0, 0, 0);
        acc3 = __builtin_amdgcn_mfma_f32_16x16x32_bf16(a, b3, acc3, 0, 0, 0);
        acc4 = __builtin_amdgcn_mfma_f32_16x16x32_bf16(a, b4, acc4, 0, 0, 0);
        acc5 = __builtin_amdgcn_mfma_f32_16x16x32_bf16(a, b5, acc5, 0, 0, 0);
        acc6 = __builtin_amdgcn_mfma_f32_16x16x32_bf16(a, b6, acc6, 0, 0, 0);
        acc7 = __builtin_amdgcn_mfma_f32_16x16x32_bf16(a, b7, acc7, 0, 0, 0);
    }

    float pS[4][4], pD[4][4];
    #pragma unroll
    for (int r = 0; r < 4; ++r)
        #pragma unroll
        for (int hd = 0; hd < 4; ++hd) { pS[r][hd] = 0.f; pD[r][hd] = 0.f; }

    #define EPI(OT, ACC) { \
        float aSv = af[(OT) * 16 + lr]; \
        float aDv = af[128 + (OT) * 16 + lr]; \
        _Pragma("unroll") \
        for (int r = 0; r < 4; ++r) { \
            int n = nb + wv * 16 + lg * 4 + r; \
            float v = ACC[r]; \
            if (n < N_NODES) h[(size_t)n * HF + (OT) * 16 + lr] = f2bf(v); \
            pS[r][(OT) >> 1] += v * aSv; \
            pD[r][(OT) >> 1] += v * aDv; \
        } }
    EPI(0, acc0) EPI(1, acc1) EPI(2, acc2) EPI(3, acc3)
    EPI(4, acc4) EPI(5, acc5) EPI(6, acc6) EPI(7, acc7)
    #undef EPI

    #pragma unroll
    for (int off = 1; off < 16; off <<= 1) {
        #pragma unroll
        for (int r = 0; r < 4; ++r)
            #pragma unroll
            for (int hd = 0; hd < 4; ++hd) {
                pS[r][hd] += __shfl_xor(pS[r][hd], off, 64);
                pD[r][hd] += __shfl_xor(pD[r][hd], off, 64);
            }
    }
    if (lr == 0) {
        #pragma unroll
        for (int r = 0; r < 4; ++r) {
            int n = nb + wv * 16 + lg * 4 + r;
            if (n < N_NODES) {
                #pragma unroll
                for (int hd = 0; hd < 4; ++hd) {
                    s_src[n * 4 + hd] = pS[r][hd];
                    s_dst[n * 4 + hd] = pD[r][hd];
                }
            }
        }
    }
}

// ---------- K3: merged per-block exclusive scans (blocks 0..48 nodes, 49..97 buckets) ----------
__global__ __launch_bounds__(1024) void k_scanA(const int* cA, int* oA, int* bA,
                                                const int* cB, int* oB, int* bB) {
    __shared__ int buf[1024];
    int t = threadIdx.x;
    bool second = blockIdx.x >= SCAN_A;
    int blk = second ? (int)blockIdx.x - SCAN_A : (int)blockIdx.x;
    const int* c = second ? cB : cA;
    int* o = second ? oB : oA;
    int* bt = second ? bB : bA;
    int n = second ? BKT_N : N_NODES;
    int i = blk * 1024 + t;
    int v = (i < n) ? c[i] : 0;
    buf[t] = v;
    __syncthreads();
    for (int off = 1; off < 1024; off <<= 1) {
        int u = (t >= off) ? buf[t - off] : 0;
        __syncthreads();
        buf[t] += u;
        __syncthreads();
    }
    if (i < n) o[i] = buf[t] - v;             // exclusive within block
    if (t == 1023) bt[blk] = buf[1023];
}

// ---------- K4: merged block-offset scans (wave 0 = nodes, wave 1 = buckets); writes totals ----------
__global__ void k_scanB(int* btA, int* oA, int* btB, int* oB) {
    int w = threadIdx.x >> 6, l = threadIdx.x & 63;   // 128 threads = 2 waves
    int* bt = w ? btB : btA;
    int* o  = w ? oB : oA;
    int nblk = w ? SCAN_B : SCAN_A;
    int n    = w ? BKT_N : N_NODES;
    int v = (l < nblk) ? bt[l] : 0;
    int inc = v;
    for (int off = 1; off < 64; off <<= 1) {
        int u = __shfl_up(inc, off, 64);
        if (l >= off) inc += u;
    }
    int tot = __shfl(inc, nblk - 1, 64);
    if (l < nblk) bt[l] = inc - v;            // exclusive block offsets
    if (l == 0) o[n] = tot;                   // final total (no correction needed)
}

// ---------- K5: scatter edges into bucket-major order (LDS returning atomics only) ----------
__global__ __launch_bounds__(256) void k_bucket1(const unsigned int* edgePk, const int* base,
                                                 const int* btot2, unsigned int* bkt) {
    __shared__ int lcur[NBKT];
    int tid = threadIdx.x, blk = blockIdx.x;
    if (tid < NBKT) {
        int idx = tid * NBLK + blk;           // < BKT_N always
        lcur[tid] = base[idx] + btot2[idx >> 10];
    }
    __syncthreads();
    int e0 = blk * EPB;
    for (int i = tid; i < EPB; i += 256) {
        unsigned int pk = edgePk[e0 + i];
        int slot = atomicAdd(&lcur[pk >> 24], 1);
        bkt[slot] = pk;
    }
}

// ---------- K6: one block per bucket -> final CSR records {src, 4xf16 scores} ----------
__global__ __launch_bounds__(256) void k_bucket2(const unsigned int* bkt, const int* base,
                                                 const int* btot2, const int* rowSt, const int* btot,
                                                 const float* s_src, const float* s_dst, uint4* recs) {
    __shared__ int lcur[256];
    int tid = threadIdx.x, bk = blockIdx.x;
    lcur[tid] = 0;
    __syncthreads();
    int i0 = bk * NBLK;
    int bstart = base[i0] + btot2[i0 >> 10];
    int i1 = (bk + 1) * NBLK;
    int bend = (i1 < BKT_N) ? (base[i1] + btot2[i1 >> 10]) : base[BKT_N];
    for (int i = bstart + tid; i < bend; i += 256) {
        unsigned int pk = bkt[i];
        int s = (int)(pk & 0xFFFFu), d = (int)(pk >> 16);
        int r = atomicAdd(&lcur[d & 255], 1);
        int slot = rowSt[d] + btot[d >> 10] + r;
        float4 ss = *(const float4*)&s_src[s * 4];
        float4 sd = *(const float4*)&s_dst[d * 4];
        unsigned int q0 = f2h(leaky(ss.x + sd.x));
        unsigned int q1 = f2h(leaky(ss.y + sd.y));
        unsigned int q2 = f2h(leaky(ss.z + sd.z));
        unsigned int q3 = f2h(leaky(ss.w + sd.w));
        uint4 rc;
        rc.x = (unsigned int)s;
        rc.y = q0 | (q1 << 16);
        rc.z = q2 | (q3 << 16);
        rc.w = 0u;
        recs[slot] = rc;
    }
}

// ---------- K7: single-pass gather-FMA aggregation (no max pre-pass; exp clamped) ----------
__global__ __launch_bounds__(256) void k_agg(const unsigned short* h, const uint4* recs,
                                             const int* rowSt, const int* btot, float* out) {
    int wid = threadIdx.x >> 6;
    int l = threadIdx.x & 63;
    int n = blockIdx.x * 4 + wid;
    if (n >= N_NODES) return;
    int rs = rowSt[n] + btot[n >> 10];
    int re = (n + 1 < N_NODES) ? (rowSt[n + 1] + btot[(n + 1) >> 10]) : rowSt[N_NODES];
    int deg = re - rs;
    int lf = l & 15, grp = l >> 4, hd = lf >> 2;
    if (deg == 0) {
        *(float2*)&out[(size_t)n * HF + lf * 8 + grp * 2] = make_float2(0.f, 0.f);
        return;
    }
    const float NI = -__builtin_inff();
    float z = 0.f;
    float a0=0,a1=0,a2=0,a3=0,a4=0,a5=0,a6=0,a7=0;

    // 1-deep software pipeline
    float sc = NI; int si = 0;
    if (grp < deg) {
        uint4 r = recs[rs + grp];
        si = (int)r.x;
        sc = h2f((unsigned short)((((hd & 2) ? r.z : r.y)) >> ((hd & 1) * 16)));
    }
    uint4 u = *(const uint4*)&h[(size_t)si * HF + lf * 8];

    for (int it = 0; it < deg; it += 4) {
        int e1 = it + 4 + grp;
        float sc1 = NI; int si1 = 0;
        if (e1 < deg) {
            uint4 r = recs[rs + e1];
            si1 = (int)r.x;
            sc1 = h2f((unsigned short)((((hd & 2) ? r.z : r.y)) >> ((hd & 1) * 16)));
        }
        uint4 u1 = *(const uint4*)&h[(size_t)si1 * HF + lf * 8];
        float w = __expf(fminf(sc, 60.f));     // 0 for invalid slots (sc = -inf)
        z += w;
        a0 += w * bf2f((unsigned short)(u.x & 0xFFFFu)); a1 += w * bf2f((unsigned short)(u.x >> 16));
        a2 += w * bf2f((unsigned short)(u.y & 0xFFFFu)); a3 += w * bf2f((unsigned short)(u.y >> 16));
        a4 += w * bf2f((unsigned short)(u.z & 0xFFFFu)); a5 += w * bf2f((unsigned short)(u.z >> 16));
        a6 += w * bf2f((unsigned short)(u.w & 0xFFFFu)); a7 += w * bf2f((unsigned short)(u.w >> 16));
        sc = sc1; si = si1; u = u1;
    }
    #pragma unroll
    for (int off = 16; off <= 32; off <<= 1) {
        z  += __shfl_xor(z,  off, 64);
        a0 += __shfl_xor(a0, off, 64); a1 += __shfl_xor(a1, off, 64);
        a2 += __shfl_xor(a2, off, 64); a3 += __shfl_xor(a3, off, 64);
        a4 += __shfl_xor(a4, off, 64); a5 += __shfl_xor(a5, off, 64);
        a6 += __shfl_xor(a6, off, 64); a7 += __shfl_xor(a7, off, 64);
    }
    float inv = 1.0f / (z + EPS_F);
    if (grp == 0) *(float4*)&out[(size_t)n * HF + lf * 8]     = make_float4(a0*inv, a1*inv, a2*inv, a3*inv);
    if (grp == 1) *(float4*)&out[(size_t)n * HF + lf * 8 + 4] = make_float4(a4*inv, a5*inv, a6*inv, a7*inv);
}

extern "C" void kernel_launch(void* const* d_in, const int* in_sizes, int n_in,
                              void* d_out, int out_size, void* d_ws, size_t ws_size,
                              hipStream_t stream) {
    const void* x     = d_in[0];
    const void* eidx  = d_in[1];
    const void* W     = d_in[2];
    const void* a_src = d_in[3];
    const void* a_dst = d_in[4];
    char* ws = (char*)d_ws;

    size_t off = 0;
    auto alloc = [&](size_t bytes) { size_t o = off; off += (bytes + 255) & ~(size_t)255; return o; };
    size_t flagsO  = alloc(64 * 4);
    size_t countsO = alloc((size_t)N_NODES * 4);
    size_t zeroEnd = off;                       // [countsO, zeroEnd) memset 0
    size_t rowO    = alloc((size_t)(N_NODES + 1) * 4);
    size_t btotO   = alloc(64 * 4);
    size_t btot2O  = alloc(64 * 4);
    size_t bhO     = alloc((size_t)BKT_N * 4);
    size_t baseO   = alloc((size_t)(BKT_N + 1) * 4);
    size_t epkO    = alloc((size_t)N_EDGES * 4);
    size_t bktO    = alloc((size_t)N_EDGES * 4);
    size_t recsO   = alloc((size_t)N_EDGES * 16);
    size_t WbO     = alloc(16384 * 2);
    size_t afO     = alloc(256 * 4);
    size_t ssO     = alloc((size_t)N_NODES * 4 * 4);
    size_t sdO     = alloc((size_t)N_NODES * 4 * 4);
    size_t hO      = alloc((size_t)N_NODES * HF * 2);
    (void)ws_size; (void)in_sizes; (void)n_in;

    int*   flags   = (int*)(ws + flagsO);
    int*   counts  = (int*)(ws + countsO);
    int*   rowSt   = (int*)(ws + rowO);
    int*   btot    = (int*)(ws + btotO);
    int*   btot2   = (int*)(ws + btot2O);
    int*   bh      = (int*)(ws + bhO);
    int*   base    = (int*)(ws + baseO);
    unsigned int* edgePk = (unsigned int*)(ws + epkO);
    unsigned int* bkt    = (unsigned int*)(ws + bktO);
    uint4* recs    = (uint4*)(ws + recsO);
    unsigned short* Wbf = (unsigned short*)(ws + WbO);
    float* af      = (float*)(ws + afO);
    float* s_src   = (float*)(ws + ssO);
    float* s_dst   = (float*)(ws + sdO);
    unsigned short* h = (unsigned short*)(ws + hO);
    float* outF    = (float*)d_out;

    hipMemsetAsync(ws + countsO, 0, zeroEnd - countsO, stream);

    k_sniff<<<1, 64, 0, stream>>>(x, eidx, flags);
    k_convert<<<NBLK, 256, 0, stream>>>(W, a_src, a_dst, eidx, Wbf, af, edgePk, counts, bh, flags);
    k_gemm<<<(N_NODES + 63) / 64, 256, 0, stream>>>(x, Wbf, af, h, s_src, s_dst, flags);
    k_scanA<<<SCAN_A + SCAN_B, 1024, 0, stream>>>(counts, rowSt, btot, bh, base, btot2);
    k_scanB<<<1, 128, 0, stream>>>(btot, rowSt, btot2, base);
    k_bucket1<<<NBLK, 256, 0, stream>>>(edgePk, base, btot2, bkt);
    k_bucket2<<<NBKT, 256, 0, stream>>>(bkt, base, btot2, rowSt, btot, s_src, s_dst, recs);
    k_agg<<<(N_NODES + 3) / 4, 256, 0, stream>>>(h, recs, rowSt, btot, outF);
}

// Round 10
// 166.233 us; speedup vs baseline: 1.3567x; 1.1744x over previous
//
#include <hip/hip_runtime.h>
#include <stdint.h>

#define N_NODES 50000
#define N_EDGES 800000
#define HF 128          // HEADS * OUT_F
#define NEG_SLOPE 0.2f
#define EPS_F 1e-8f
#define NBKT 196        // buckets = dst>>8, dst<50000 -> 0..195
#define NBLK 256        // blocks in convert/bucket1 passes
#define EPB (N_EDGES / NBLK)   // 3125, exact
#define BKT_N (NBKT * NBLK)    // 50176
#define SCAN_B 49              // blocks for bucket scan (49*1024 == 50176)

typedef __attribute__((ext_vector_type(8))) short short8;
typedef __attribute__((ext_vector_type(4))) float f32x4;

// ---------- helpers ----------
__device__ __forceinline__ float bf2f(unsigned short u) {
    union { unsigned int i; float f; } v; v.i = ((unsigned int)u) << 16; return v.f;
}
__device__ __forceinline__ unsigned short f2bf(float f) {
    union { unsigned int i; float f; } v; v.f = f;
    unsigned int b = v.i;
    unsigned int r = (b + 0x7FFFu + ((b >> 16) & 1u)) >> 16;   // round-to-nearest-even
    return (unsigned short)r;
}
__device__ __forceinline__ float leaky(float v) { return v > 0.f ? v : NEG_SLOPE * v; }
__device__ __forceinline__ unsigned short f2h(float f) {
    _Float16 h = (_Float16)f; unsigned short u; __builtin_memcpy(&u, &h, 2); return u;
}
__device__ __forceinline__ float h2f(unsigned short u) {
    _Float16 h; __builtin_memcpy(&h, &u, 2); return (float)h;
}
// inline dtype sniff: first wave inspects data, result broadcast via LDS.
// deterministic (same 64 elements) -> consistent across all blocks/kernels.
__device__ __forceinline__ void sniff_wave(const void* x, const void* eidx, int tid,
                                           volatile int* sf) {
    if (tid < 64) {
        const unsigned short* xu = (const unsigned short*)x;
        float f = bf2f(xu[2 * tid]);
        float af = fabsf(f);
        bool extreme = !(af <= 1e6f) || (f != 0.0f && af < 1e-7f);
        unsigned long long mask = __ballot(extreme);
        if (eidx) {
            const unsigned int* eu = (const unsigned int*)eidx;
            unsigned long long mask2 = __ballot(eu[2 * tid + 1] != 0u);
            if (tid == 0) sf[1] = (__popcll(mask2) >= 4) ? 0 : 1;   // 1 = int64
        }
        if (tid == 0) sf[0] = (__popcll(mask) >= 8) ? 0 : 1;        // 1 = bf16
    }
}

// ---------- K1: convert W/a, pack edges, fused bucket histogram (inline sniff) ----------
// 256 blocks x 256 threads. blocks 0..63 also convert W; block 64 converts a_src/a_dst.
__global__ __launch_bounds__(256) void k_convert(const void* W, const void* a_src, const void* a_dst,
                                                 const void* x, const void* eidx,
                                                 unsigned short* Wbf, float* af,
                                                 unsigned int* edgePk, int* bh) {
    __shared__ int lh[NBKT];
    __shared__ int sf[2];
    int tid = threadIdx.x, blk = blockIdx.x;
    if (tid < NBKT) lh[tid] = 0;
    sniff_wave(x, eidx, tid, sf);
    __syncthreads();
    int isB = sf[0], is64 = sf[1];
    if (blk < 64) {
        int i = blk * 256 + tid;   // 16384 W elements
        Wbf[i] = isB ? ((const unsigned short*)W)[i] : f2bf(((const float*)W)[i]);
    } else if (blk == 64 && tid < 128) {
        af[tid]       = isB ? bf2f(((const unsigned short*)a_src)[tid]) : ((const float*)a_src)[tid];
        af[128 + tid] = isB ? bf2f(((const unsigned short*)a_dst)[tid]) : ((const float*)a_dst)[tid];
    }
    int e0 = blk * EPB;
    for (int i = tid; i < EPB; i += 256) {
        int e = e0 + i;
        int s, d;
        if (is64) {
            s = (int)((const long long*)eidx)[e];
            d = (int)((const long long*)eidx)[N_EDGES + e];
        } else {
            s = ((const int*)eidx)[e];
            d = ((const int*)eidx)[N_EDGES + e];
        }
        edgePk[e] = (unsigned int)s | ((unsigned int)d << 16);
        atomicAdd(&lh[d >> 8], 1);    // LDS histogram only
    }
    __syncthreads();
    if (tid < NBKT) bh[tid * NBLK + blk] = lh[tid];   // bucket-major
}

// ---------- K2: MFMA GEMM  h = x @ W^T (bf16), fused scores s_src/s_dst (inline sniff) ----------
__global__ __launch_bounds__(256) void k_gemm(const void* x, const unsigned short* Wbf, const float* af,
                                              unsigned short* h, float* s_src, float* s_dst) {
    __shared__ short xl[64 * 136];    // [row][k] bf16, padded
    __shared__ short wl[128 * 136];   // [o][k] bf16, padded
    __shared__ int sf[2];
    int tid = threadIdx.x;
    int nb = blockIdx.x * 64;
    const unsigned short* xu = (const unsigned short*)x;
    const float* xf = (const float*)x;

    sniff_wave(x, nullptr, tid, sf);
    __syncthreads();
    int isB = sf[0];

    #pragma unroll
    for (int it = 0; it < 8; ++it) {
        int o = (tid >> 4) + it * 16;
        int k8 = (tid & 15) * 8;
        *(short8*)&wl[o * 136 + k8] = *(const short8*)&Wbf[o * 128 + k8];
    }
    #pragma unroll
    for (int it = 0; it < 4; ++it) {
        int row = (tid >> 4) + it * 16;
        int k8 = (tid & 15) * 8;
        int node = nb + row;
        short8 val;
        if (node < N_NODES) {
            if (isB) {
                val = *(const short8*)&xu[(size_t)node * 128 + k8];
            } else {
                float4 f0 = *(const float4*)&xf[(size_t)node * 128 + k8];
                float4 f1 = *(const float4*)&xf[(size_t)node * 128 + k8 + 4];
                val[0] = (short)f2bf(f0.x); val[1] = (short)f2bf(f0.y);
                val[2] = (short)f2bf(f0.z); val[3] = (short)f2bf(f0.w);
                val[4] = (short)f2bf(f1.x); val[5] = (short)f2bf(f1.y);
                val[6] = (short)f2bf(f1.z); val[7] = (short)f2bf(f1.w);
            }
        } else {
            val = short8{0,0,0,0,0,0,0,0};
        }
        *(short8*)&xl[row * 136 + k8] = val;
    }
    __syncthreads();

    int wv = tid >> 6, l = tid & 63;
    int lr = l & 15, lg = l >> 4;

    f32x4 acc0 = {0,0,0,0}, acc1 = {0,0,0,0}, acc2 = {0,0,0,0}, acc3 = {0,0,0,0};
    f32x4 acc4 = {0,0,0,0}, acc5 = {0,0,0,0}, acc6 = {0,0,0,0}, acc7 = {0,0,0,0};
    #pragma unroll
    for (int kb = 0; kb < 4; ++kb) {
        short8 a = *(const short8*)&xl[(wv * 16 + lr) * 136 + kb * 32 + lg * 8];
        short8 b0 = *(const short8*)&wl[(0 * 16 + lr) * 136 + kb * 32 + lg * 8];
        short8 b1 = *(const short8*)&wl[(1 * 16 + lr) * 136 + kb * 32 + lg * 8];
        short8 b2 = *(const short8*)&wl[(2 * 16 + lr) * 136 + kb * 32 + lg * 8];
        short8 b3 = *(const short8*)&wl[(3 * 16 + lr) * 136 + kb * 32 + lg * 8];
        short8 b4 = *(const short8*)&wl[(4 * 16 + lr) * 136 + kb * 32 + lg * 8];
        short8 b5 = *(const short8*)&wl[(5 * 16 + lr) * 136 + kb * 32 + lg * 8];
        short8 b6 = *(const short8*)&wl[(6 * 16 + lr) * 136 + kb * 32 + lg * 8];
        short8 b7 = *(const short8*)&wl[(7 * 16 + lr) * 136 + kb * 32 + lg * 8];
        acc0 = __builtin_amdgcn_mfma_f32_16x16x32_bf16(a, b0, acc0, 0, 0, 0);
        acc1 = __builtin_amdgcn_mfma_f32_16x16x32_bf16(a, b1, acc1, 0, 0, 0);
        acc2 = __builtin_amdgcn_mfma_f32_16x16x32_bf16(a, b2, acc2, 0, 0, 0);
        acc3 = __builtin_amdgcn_mfma_f32_16x16x32_bf16(a, b3, acc3, 0, 0, 0);
        acc4 = __builtin_amdgcn_mfma_f32_16x16x32_bf16(a, b4, acc4, 0, 0, 0);
        acc5 = __builtin_amdgcn_mfma_f32_16x16x32_bf16(a, b5, acc5, 0, 0, 0);
        acc6 = __builtin_amdgcn_mfma_f32_16x16x32_bf16(a, b6, acc6, 0, 0, 0);
        acc7 = __builtin_amdgcn_mfma_f32_16x16x32_bf16(a, b7, acc7, 0, 0, 0);
    }

    float pS[4][4], pD[4][4];
    #pragma unroll
    for (int r = 0; r < 4; ++r)
        #pragma unroll
        for (int hd = 0; hd < 4; ++hd) { pS[r][hd] = 0.f; pD[r][hd] = 0.f; }

    #define EPI(OT, ACC) { \
        float aSv = af[(OT) * 16 + lr]; \
        float aDv = af[128 + (OT) * 16 + lr]; \
        _Pragma("unroll") \
        for (int r = 0; r < 4; ++r) { \
            int n = nb + wv * 16 + lg * 4 + r; \
            float v = ACC[r]; \
            if (n < N_NODES) h[(size_t)n * HF + (OT) * 16 + lr] = f2bf(v); \
            pS[r][(OT) >> 1] += v * aSv; \
            pD[r][(OT) >> 1] += v * aDv; \
        } }
    EPI(0, acc0) EPI(1, acc1) EPI(2, acc2) EPI(3, acc3)
    EPI(4, acc4) EPI(5, acc5) EPI(6, acc6) EPI(7, acc7)
    #undef EPI

    #pragma unroll
    for (int off = 1; off < 16; off <<= 1) {
        #pragma unroll
        for (int r = 0; r < 4; ++r)
            #pragma unroll
            for (int hd = 0; hd < 4; ++hd) {
                pS[r][hd] += __shfl_xor(pS[r][hd], off, 64);
                pD[r][hd] += __shfl_xor(pD[r][hd], off, 64);
            }
    }
    if (lr == 0) {
        #pragma unroll
        for (int r = 0; r < 4; ++r) {
            int n = nb + wv * 16 + lg * 4 + r;
            if (n < N_NODES) {
                #pragma unroll
                for (int hd = 0; hd < 4; ++hd) {
                    s_src[n * 4 + hd] = pS[r][hd];
                    s_dst[n * 4 + hd] = pD[r][hd];
                }
            }
        }
    }
}

// ---------- K3: per-block exclusive scan of bucket histogram ----------
__global__ __launch_bounds__(1024) void k_scanA(const int* c, int* o, int* bt) {
    __shared__ int buf[1024];
    int t = threadIdx.x;
    int i = blockIdx.x * 1024 + t;
    int v = (i < BKT_N) ? c[i] : 0;
    buf[t] = v;
    __syncthreads();
    for (int off = 1; off < 1024; off <<= 1) {
        int u = (t >= off) ? buf[t - off] : 0;
        __syncthreads();
        buf[t] += u;
        __syncthreads();
    }
    if (i < BKT_N) o[i] = buf[t] - v;             // exclusive within block
    if (t == 1023) bt[blockIdx.x] = buf[1023];
}

// ---------- K4: block-offset scan (single wave) ----------
__global__ void k_scanB(int* bt) {
    int l = threadIdx.x;  // 64 threads
    int v = (l < SCAN_B) ? bt[l] : 0;
    int inc = v;
    for (int off = 1; off < 64; off <<= 1) {
        int u = __shfl_up(inc, off, 64);
        if (l >= off) inc += u;
    }
    if (l < SCAN_B) bt[l] = inc - v;              // exclusive block offsets
}

// ---------- K5: scatter edges into bucket-major order (LDS returning atomics only) ----------
__global__ __launch_bounds__(256) void k_bucket1(const unsigned int* edgePk, const int* base,
                                                 const int* btot2, unsigned int* bkt) {
    __shared__ int lcur[NBKT];
    int tid = threadIdx.x, blk = blockIdx.x;
    if (tid < NBKT) {
        int idx = tid * NBLK + blk;           // < BKT_N always
        lcur[tid] = base[idx] + btot2[idx >> 10];
    }
    __syncthreads();
    int e0 = blk * EPB;
    for (int i = tid; i < EPB; i += 256) {
        unsigned int pk = edgePk[e0 + i];
        int slot = atomicAdd(&lcur[pk >> 24], 1);
        bkt[slot] = pk;
    }
}

// ---------- K6: one block per bucket -> node-local CSR (writes rowSt + records) ----------
__global__ __launch_bounds__(256) void k_bucket2(const unsigned int* bkt, const int* base,
                                                 const int* btot2, int* rowSt,
                                                 const float* s_src, const float* s_dst, uint4* recs) {
    __shared__ int lhist[256];
    __shared__ int buf[256];
    __shared__ int lexcl[256];
    __shared__ int lcur[256];
    int tid = threadIdx.x, bk = blockIdx.x;
    lhist[tid] = 0; lcur[tid] = 0;
    __syncthreads();
    int i0 = bk * NBLK;
    int bstart = base[i0] + btot2[i0 >> 10];
    int i1 = (bk + 1) * NBLK;
    int bend = (i1 < BKT_N) ? (base[i1] + btot2[i1 >> 10]) : N_EDGES;
    // pass 1: per-node counts within bucket
    for (int i = bstart + tid; i < bend; i += 256)
        atomicAdd(&lhist[(bkt[i] >> 16) & 255], 1);
    __syncthreads();
    // 256-entry exclusive scan
    int v = lhist[tid];
    buf[tid] = v;
    __syncthreads();
    for (int off = 1; off < 256; off <<= 1) {
        int u = (tid >= off) ? buf[tid - off] : 0;
        __syncthreads();
        buf[tid] += u;
        __syncthreads();
    }
    lexcl[tid] = buf[tid] - v;
    int node = bk * 256 + tid;
    if (node < N_NODES) rowSt[node] = bstart + lexcl[tid];
    __syncthreads();
    // pass 2: write final records
    for (int i = bstart + tid; i < bend; i += 256) {
        unsigned int pk = bkt[i];
        int s = (int)(pk & 0xFFFFu), d8 = (int)((pk >> 16) & 255);
        int r = atomicAdd(&lcur[d8], 1);
        int slot = bstart + lexcl[d8] + r;
        int d = (int)(pk >> 16);
        float4 ss = *(const float4*)&s_src[s * 4];
        float4 sd = *(const float4*)&s_dst[d * 4];
        unsigned int q0 = f2h(leaky(ss.x + sd.x));
        unsigned int q1 = f2h(leaky(ss.y + sd.y));
        unsigned int q2 = f2h(leaky(ss.z + sd.z));
        unsigned int q3 = f2h(leaky(ss.w + sd.w));
        uint4 rc;
        rc.x = (unsigned int)s;
        rc.y = q0 | (q1 << 16);
        rc.z = q2 | (q3 << 16);
        rc.w = 0u;
        recs[slot] = rc;
    }
}

// ---------- K7: single-pass gather-FMA aggregation (exp clamped; no max pre-pass) ----------
__global__ __launch_bounds__(256) void k_agg(const unsigned short* h, const uint4* recs,
                                             const int* rowSt, float* out) {
    int wid = threadIdx.x >> 6;
    int l = threadIdx.x & 63;
    int n = blockIdx.x * 4 + wid;
    if (n >= N_NODES) return;
    int rs = rowSt[n];
    int re = (n + 1 < N_NODES) ? rowSt[n + 1] : N_EDGES;
    int deg = re - rs;
    int lf = l & 15, grp = l >> 4, hd = lf >> 2;
    if (deg == 0) {
        *(float2*)&out[(size_t)n * HF + lf * 8 + grp * 2] = make_float2(0.f, 0.f);
        return;
    }
    const float NI = -__builtin_inff();
    float z = 0.f;
    float a0=0,a1=0,a2=0,a3=0,a4=0,a5=0,a6=0,a7=0;

    // 1-deep software pipeline
    float sc = NI; int si = 0;
    if (grp < deg) {
        uint4 r = recs[rs + grp];
        si = (int)r.x;
        sc = h2f((unsigned short)((((hd & 2) ? r.z : r.y)) >> ((hd & 1) * 16)));
    }
    uint4 u = *(const uint4*)&h[(size_t)si * HF + lf * 8];

    for (int it = 0; it < deg; it += 4) {
        int e1 = it + 4 + grp;
        float sc1 = NI; int si1 = 0;
        if (e1 < deg) {
            uint4 r = recs[rs + e1];
            si1 = (int)r.x;
            sc1 = h2f((unsigned short)((((hd & 2) ? r.z : r.y)) >> ((hd & 1) * 16)));
        }
        uint4 u1 = *(const uint4*)&h[(size_t)si1 * HF + lf * 8];
        float w = __expf(fminf(sc, 60.f));     // 0 for invalid slots (sc = -inf)
        z += w;
        a0 += w * bf2f((unsigned short)(u.x & 0xFFFFu)); a1 += w * bf2f((unsigned short)(u.x >> 16));
        a2 += w * bf2f((unsigned short)(u.y & 0xFFFFu)); a3 += w * bf2f((unsigned short)(u.y >> 16));
        a4 += w * bf2f((unsigned short)(u.z & 0xFFFFu)); a5 += w * bf2f((unsigned short)(u.z >> 16));
        a6 += w * bf2f((unsigned short)(u.w & 0xFFFFu)); a7 += w * bf2f((unsigned short)(u.w >> 16));
        sc = sc1; si = si1; u = u1;
    }
    #pragma unroll
    for (int off = 16; off <= 32; off <<= 1) {
        z  += __shfl_xor(z,  off, 64);
        a0 += __shfl_xor(a0, off, 64); a1 += __shfl_xor(a1, off, 64);
        a2 += __shfl_xor(a2, off, 64); a3 += __shfl_xor(a3, off, 64);
        a4 += __shfl_xor(a4, off, 64); a5 += __shfl_xor(a5, off, 64);
        a6 += __shfl_xor(a6, off, 64); a7 += __shfl_xor(a7, off, 64);
    }
    float inv = 1.0f / (z + EPS_F);
    if (grp == 0) *(float4*)&out[(size_t)n * HF + lf * 8]     = make_float4(a0*inv, a1*inv, a2*inv, a3*inv);
    if (grp == 1) *(float4*)&out[(size_t)n * HF + lf * 8 + 4] = make_float4(a4*inv, a5*inv, a6*inv, a7*inv);
}

extern "C" void kernel_launch(void* const* d_in, const int* in_sizes, int n_in,
                              void* d_out, int out_size, void* d_ws, size_t ws_size,
                              hipStream_t stream) {
    const void* x     = d_in[0];
    const void* eidx  = d_in[1];
    const void* W     = d_in[2];
    const void* a_src = d_in[3];
    const void* a_dst = d_in[4];
    char* ws = (char*)d_ws;

    size_t off = 0;
    auto alloc = [&](size_t bytes) { size_t o = off; off += (bytes + 255) & ~(size_t)255; return o; };
    size_t rowO    = alloc((size_t)(N_NODES + 1) * 4);
    size_t btot2O  = alloc(64 * 4);
    size_t bhO     = alloc((size_t)BKT_N * 4);
    size_t baseO   = alloc((size_t)(BKT_N + 1) * 4);
    size_t epkO    = alloc((size_t)N_EDGES * 4);
    size_t bktO    = alloc((size_t)N_EDGES * 4);
    size_t recsO   = alloc((size_t)N_EDGES * 16);
    size_t WbO     = alloc(16384 * 2);
    size_t afO     = alloc(256 * 4);
    size_t ssO     = alloc((size_t)N_NODES * 4 * 4);
    size_t sdO     = alloc((size_t)N_NODES * 4 * 4);
    size_t hO      = alloc((size_t)N_NODES * HF * 2);
    (void)ws_size; (void)in_sizes; (void)n_in;

    int*   rowSt   = (int*)(ws + rowO);
    int*   btot2   = (int*)(ws + btot2O);
    int*   bh      = (int*)(ws + bhO);
    int*   base    = (int*)(ws + baseO);
    unsigned int* edgePk = (unsigned int*)(ws + epkO);
    unsigned int* bkt    = (unsigned int*)(ws + bktO);
    uint4* recs    = (uint4*)(ws + recsO);
    unsigned short* Wbf = (unsigned short*)(ws + WbO);
    float* af      = (float*)(ws + afO);
    float* s_src   = (float*)(ws + ssO);
    float* s_dst   = (float*)(ws + sdO);
    unsigned short* h = (unsigned short*)(ws + hO);
    float* outF    = (float*)d_out;

    k_convert<<<NBLK, 256, 0, stream>>>(W, a_src, a_dst, x, eidx, Wbf, af, edgePk, bh);
    k_gemm<<<(N_NODES + 63) / 64, 256, 0, stream>>>(x, Wbf, af, h, s_src, s_dst);
    k_scanA<<<SCAN_B, 1024, 0, stream>>>(bh, base, btot2);
    k_scanB<<<1, 64, 0, stream>>>(btot2);
    k_bucket1<<<NBLK, 256, 0, stream>>>(edgePk, base, btot2, bkt);
    k_bucket2<<<NBKT, 256, 0, stream>>>(bkt, base, btot2, rowSt, s_src, s_dst, recs);
    k_agg<<<(N_NODES + 3) / 4, 256, 0, stream>>>(h, recs, rowSt, outF);
}